// Round 2
// baseline (344.001 us; speedup 1.0000x reference)
//
#include <hip/hip_runtime.h>

#define N_TR 1024
#define H_DIM 128
#define P_PAIRS 523776   // N*(N-1)/2
// ws float offsets
#define WS_U  0
#define WS_V  131072
#define WS_UA 262144
#define WS_VA 393216
#define WS_FRAG_BYTES 2097152   // byte offset of frag region (after 4*N*128 f32)

typedef __attribute__((ext_vector_type(8))) short bf16x8;
typedef __attribute__((ext_vector_type(4))) float f32x4;

__device__ __forceinline__ short f2bfs(float f) {
  unsigned x = __float_as_uint(f);
  unsigned r = x + 0x7fffu + ((x >> 16) & 1u);
  return (short)(r >> 16);
}
__device__ __forceinline__ float geluf(float x) {
  return 0.5f * x * (1.0f + erff(x * 0.70710678118654752f));
}
__device__ __forceinline__ float sigmoidf_(float x) {
  return 1.0f / (1.0f + __expf(-x));
}

// ---------------- K1: U/V/Ua/Va precompute --------------------------------
// grid 128, block 256. Block handles 8 embedding rows.
// threads t<128: cons net (k=t); t>=128: assoc net (k=t-128).
__global__ __launch_bounds__(256) void k_uv(
    const float* __restrict__ emb,
    const float* __restrict__ cW1, const float* __restrict__ cb1,
    const float* __restrict__ aW1, const float* __restrict__ ab1,
    float* __restrict__ ws)
{
  __shared__ __align__(16) float sE[8][128];
  const int b = blockIdx.x;
  const int t = threadIdx.x;
  for (int idx = t; idx < 1024; idx += 256) {
    int r = idx >> 7, c = idx & 127;
    sE[r][c] = emb[(b * 8 + r) * 128 + c];
  }
  __syncthreads();
  const int k = t & 127;
  const bool cons = (t < 128);
  const float* W    = cons ? cW1 : aW1;
  const float* bias = cons ? cb1 : ab1;
  float* outU = ws + (cons ? WS_U : WS_UA);
  float* outV = ws + (cons ? WS_V : WS_VA);
  float accU[8] = {0,0,0,0,0,0,0,0};
  float accV[8] = {0,0,0,0,0,0,0,0};
  for (int c = 0; c < 128; ++c) {
    float wt = W[c * 128 + k];
    float wb = W[(128 + c) * 128 + k];
    #pragma unroll
    for (int r = 0; r < 8; ++r) {
      accU[r] += sE[r][c] * wt;
      accV[r] += sE[r][c] * wb;
    }
  }
  const float bv = bias[k];
  #pragma unroll
  for (int r = 0; r < 8; ++r) {
    outU[(b * 8 + r) * 128 + k] = accU[r];
    outV[(b * 8 + r) * 128 + k] = accV[r] + bv;
  }
}

// ---------------- K2: repack W2 matrices into MFMA B-frag order (f32->bf16)
// fragC[nt<4][ks<4][lane<64][j<8] = cW2[(ks*32+(lane>>4)*8+j)*64 + nt*16+(lane&15)]
// fragA (offset 8192) same with 32-wide N (nt<2).
__global__ __launch_bounds__(256) void k_repack(
    const float* __restrict__ cW2,
    const float* __restrict__ aW2,
    unsigned short* __restrict__ frag)
{
  int t = blockIdx.x * 256 + threadIdx.x;  // grid 48 -> 12288
  if (t < 8192) {
    int j = t & 7, lane = (t >> 3) & 63, ks = (t >> 9) & 3, nt = t >> 11;
    frag[t] = (unsigned short)f2bfs(cW2[(ks * 32 + (lane >> 4) * 8 + j) * 64 + nt * 16 + (lane & 15)]);
  } else {
    int u = t - 8192;
    int j = u & 7, lane = (u >> 3) & 63, ks = (u >> 9) & 3, nt = u >> 11;
    frag[t] = (unsigned short)f2bfs(aW2[(ks * 32 + (lane >> 4) * 8 + j) * 32 + nt * 16 + (lane & 15)]);
  }
}

// ---------------- K3: importance head (one wave per trace) ----------------
__global__ __launch_bounds__(256) void k_imp(
    const float* __restrict__ emb, const float* __restrict__ tf,
    const float* __restrict__ iW1, const float* __restrict__ ib1,
    const float* __restrict__ iW2, const float* __restrict__ ib2,
    float* __restrict__ out)
{
  const int wave = threadIdx.x >> 6, lane = threadIdx.x & 63;
  const int r = blockIdx.x * 4 + wave;
  float acc = 0.f;
  for (int c = 0; c < 128; ++c)
    acc += emb[r * 128 + c] * iW1[c * 64 + lane];
  for (int c = 0; c < 5; ++c)
    acc += tf[r * 5 + c] * iW1[(128 + c) * 64 + lane];
  float h = geluf(acc + ib1[lane]);
  float d = h * iW2[lane];
  #pragma unroll
  for (int msk = 32; msk; msk >>= 1) d += __shfl_xor(d, msk, 64);
  if (lane == 0) out[2 * P_PAIRS + r] = sigmoidf_(d + ib2[0]);
}

// ---------------- K4: pair kernel -----------------------------------------
// grid (16 j-tiles, 1024 i). Block: 4 waves; wave w owns j = jt*64+w*16+(0..15).
// lane: m = lane&15 -> pair row, g = lane>>4 -> k-group. Phase-1 results land
// directly in MFMA A-frag layout A[m=lane&15][k=g*8+s (+32*ks)].
__global__ __launch_bounds__(256) void k_pairs(
    const float* __restrict__ ws, const unsigned short* __restrict__ frag,
    const float* __restrict__ lng, const float* __restrict__ lnb,
    const float* __restrict__ cb2, const float* __restrict__ cW3,
    const float* __restrict__ cb3,
    const float* __restrict__ ab2, const float* __restrict__ aW3,
    const float* __restrict__ ab3,
    float* __restrict__ out)
{
  const int i  = blockIdx.y;
  const int jt = blockIdx.x;
  if (jt * 64 + 63 <= i) return;   // no j > i in this tile

  __shared__ __align__(16) float sU[128];
  __shared__ __align__(16) float sUa[128];
  __shared__ __align__(16) float sG[128];
  __shared__ __align__(16) float sB[128];
  __shared__ __align__(16) unsigned short sFrag[12288];
  const int t = threadIdx.x;
  {
    const uint4* src = (const uint4*)frag;
    uint4* dst = (uint4*)sFrag;
    #pragma unroll
    for (int q = 0; q < 6; ++q) dst[t + q * 256] = src[t + q * 256];
  }
  if (t < 128) {
    sU[t]  = ws[WS_U  + i * 128 + t];
    sUa[t] = ws[WS_UA + i * 128 + t];
    sG[t]  = lng[t];
    sB[t]  = lnb[t];
  }
  __syncthreads();

  const int lane = t & 63;
  const int wave = t >> 6;
  const int m = lane & 15;
  const int g = lane >> 4;
  const int j = jt * 64 + wave * 16 + m;
  const float* Vrow  = ws + WS_V  + j * 128;
  const float* Varow = ws + WS_VA + j * 128;

  // ---- consolidation phase 1: x = U(i)+V(j), LayerNorm stats ----
  float xc[4][8];
  float s1 = 0.f, s2 = 0.f;
  #pragma unroll
  for (int ks = 0; ks < 4; ++ks) {
    const int off = ks * 32 + g * 8;
    float4 v0 = *(const float4*)(Vrow + off);
    float4 v1 = *(const float4*)(Vrow + off + 4);
    float4 u0 = *(const float4*)(sU + off);
    float4 u1 = *(const float4*)(sU + off + 4);
    float xs[8] = {u0.x + v0.x, u0.y + v0.y, u0.z + v0.z, u0.w + v0.w,
                   u1.x + v1.x, u1.y + v1.y, u1.z + v1.z, u1.w + v1.w};
    #pragma unroll
    for (int s = 0; s < 8; ++s) { xc[ks][s] = xs[s]; s1 += xs[s]; s2 += xs[s] * xs[s]; }
  }
  // reduce across the 4 lanes sharing this pair (masks 16, 32)
  s1 += __shfl_xor(s1, 16, 64); s2 += __shfl_xor(s2, 16, 64);
  s1 += __shfl_xor(s1, 32, 64); s2 += __shfl_xor(s2, 32, 64);
  const float mean = s1 * 0.0078125f;
  const float var  = s2 * 0.0078125f - mean * mean;
  const float rstd = rsqrtf(var + 1e-5f);

  bf16x8 fC[4];
  #pragma unroll
  for (int ks = 0; ks < 4; ++ks) {
    const int off = ks * 32 + g * 8;
    float4 g0 = *(const float4*)(sG + off);
    float4 g1 = *(const float4*)(sG + off + 4);
    float4 b0 = *(const float4*)(sB + off);
    float4 b1 = *(const float4*)(sB + off + 4);
    float gg[8] = {g0.x, g0.y, g0.z, g0.w, g1.x, g1.y, g1.z, g1.w};
    float bb[8] = {b0.x, b0.y, b0.z, b0.w, b1.x, b1.y, b1.z, b1.w};
    #pragma unroll
    for (int s = 0; s < 8; ++s) {
      float y = (xc[ks][s] - mean) * rstd * gg[s] + bb[s];
      fC[ks][s] = f2bfs(geluf(y));
    }
  }

  // ---- association phase 1: relu(Ua(i)+Va(j)) ----
  bf16x8 fA[4];
  #pragma unroll
  for (int ks = 0; ks < 4; ++ks) {
    const int off = ks * 32 + g * 8;
    float4 v0 = *(const float4*)(Varow + off);
    float4 v1 = *(const float4*)(Varow + off + 4);
    float4 u0 = *(const float4*)(sUa + off);
    float4 u1 = *(const float4*)(sUa + off + 4);
    float rs[8] = {u0.x + v0.x, u0.y + v0.y, u0.z + v0.z, u0.w + v0.w,
                   u1.x + v1.x, u1.y + v1.y, u1.z + v1.z, u1.w + v1.w};
    #pragma unroll
    for (int s = 0; s < 8; ++s) fA[ks][s] = f2bfs(fmaxf(rs[s], 0.f));
  }

  // ---- layer-2 GEMMs via MFMA ----
  const f32x4 zero = {0.f, 0.f, 0.f, 0.f};
  f32x4 accC[4] = {zero, zero, zero, zero};
  f32x4 accA[2] = {zero, zero};
  const bf16x8* bfr = (const bf16x8*)sFrag;
  #pragma unroll
  for (int ks = 0; ks < 4; ++ks) {
    #pragma unroll
    for (int nt = 0; nt < 4; ++nt)
      accC[nt] = __builtin_amdgcn_mfma_f32_16x16x32_bf16(
          fC[ks], bfr[(nt * 4 + ks) * 64 + lane], accC[nt], 0, 0, 0);
    #pragma unroll
    for (int nt = 0; nt < 2; ++nt)
      accA[nt] = __builtin_amdgcn_mfma_f32_16x16x32_bf16(
          fA[ks], bfr[1024 + (nt * 4 + ks) * 64 + lane], accA[nt], 0, 0, 0);
  }

  // ---- layer 3: bias + act + dot with W3, reduce over n (lane&15) ----
  // C layout: col n = lane&15, pair row = g*4 + reg.
  float sc[4] = {0.f, 0.f, 0.f, 0.f};
  float sa[4] = {0.f, 0.f, 0.f, 0.f};
  #pragma unroll
  for (int nt = 0; nt < 4; ++nt) {
    const float cb = cb2[nt * 16 + m];
    const float w3 = cW3[nt * 16 + m];
    #pragma unroll
    for (int r = 0; r < 4; ++r) sc[r] += geluf(accC[nt][r] + cb) * w3;
  }
  #pragma unroll
  for (int nt = 0; nt < 2; ++nt) {
    const float ab = ab2[nt * 16 + m];
    const float w3 = aW3[nt * 16 + m];
    #pragma unroll
    for (int r = 0; r < 4; ++r) sa[r] += fmaxf(accA[nt][r] + ab, 0.f) * w3;
  }
  #pragma unroll
  for (int msk = 1; msk <= 8; msk <<= 1) {
    #pragma unroll
    for (int r = 0; r < 4; ++r) {
      sc[r] += __shfl_xor(sc[r], msk, 64);
      sa[r] += __shfl_xor(sa[r], msk, 64);
    }
  }
  if (m < 4) {
    const int jr = jt * 64 + wave * 16 + g * 4 + m;   // pair row g*4 + reg(m)
    if (jr > i) {
      const int p = i * (2 * N_TR - i - 1) / 2 + (jr - i - 1);
      out[p]           = sigmoidf_(sc[m] + cb3[0]);
      out[P_PAIRS + p] = sigmoidf_(sa[m] + ab3[0]);
    }
  }
}

extern "C" void kernel_launch(void* const* d_in, const int* in_sizes, int n_in,
                              void* d_out, int out_size, void* d_ws, size_t ws_size,
                              hipStream_t stream) {
  const float* emb = (const float*)d_in[0];
  const float* tf  = (const float*)d_in[1];
  const float* cW1 = (const float*)d_in[2];
  const float* cb1 = (const float*)d_in[3];
  const float* lng = (const float*)d_in[4];
  const float* lnb = (const float*)d_in[5];
  const float* cW2 = (const float*)d_in[6];
  const float* cb2 = (const float*)d_in[7];
  const float* cW3 = (const float*)d_in[8];
  const float* cb3 = (const float*)d_in[9];
  const float* aW1 = (const float*)d_in[10];
  const float* ab1 = (const float*)d_in[11];
  const float* aW2 = (const float*)d_in[12];
  const float* ab2 = (const float*)d_in[13];
  const float* aW3 = (const float*)d_in[14];
  const float* ab3 = (const float*)d_in[15];
  const float* iW1 = (const float*)d_in[16];
  const float* ib1 = (const float*)d_in[17];
  const float* iW2 = (const float*)d_in[18];
  const float* ib2 = (const float*)d_in[19];

  float* ws = (float*)d_ws;
  unsigned short* frag = (unsigned short*)((char*)d_ws + WS_FRAG_BYTES);
  float* out = (float*)d_out;

  hipLaunchKernelGGL(k_uv, dim3(128), dim3(256), 0, stream, emb, cW1, cb1, aW1, ab1, ws);
  hipLaunchKernelGGL(k_repack, dim3(48), dim3(256), 0, stream, cW2, aW2, frag);
  hipLaunchKernelGGL(k_imp, dim3(256), dim3(256), 0, stream, emb, tf, iW1, ib1, iW2, ib2, out);
  hipLaunchKernelGGL(k_pairs, dim3(16, 1024), dim3(256), 0, stream,
                     ws, frag, lng, lnb, cb2, cW3, cb3, ab2, aW3, ab3, out);
}

// Round 3
// 236.242 us; speedup vs baseline: 1.4561x; 1.4561x over previous
//
#include <hip/hip_runtime.h>

#define N_TR 1024
#define H_DIM 128
#define P_PAIRS 523776   // N*(N-1)/2
#define TI 8             // i-rows per k_pairs block
// ws float offsets
#define WS_U  0
#define WS_V  131072
#define WS_UA 262144
#define WS_VA 393216
#define WS_FRAG_BYTES 2097152   // byte offset of frag region (after 4*N*128 f32)

typedef __attribute__((ext_vector_type(8))) short bf16x8;
typedef __attribute__((ext_vector_type(4))) float f32x4;

__device__ __forceinline__ short f2bfs(float f) {
  unsigned x = __float_as_uint(f);
  unsigned r = x + 0x7fffu + ((x >> 16) & 1u);
  return (short)(r >> 16);
}
// pack two f32 -> two bf16 (round-half-up) in one word: hi=f1, lo=f0
__device__ __forceinline__ unsigned pk_bf16(float f0, float f1) {
  unsigned a0 = __float_as_uint(f0) + 0x8000u;
  unsigned a1 = __float_as_uint(f1) + 0x8000u;
  return __builtin_amdgcn_perm(a1, a0, 0x07060302u);
}
// branch-free tanh-form GELU: x - x/(exp(2z)+1), z = 0.79788456(x+0.044715x^3)
__device__ __forceinline__ float geluf(float x) {
  float u = x * x;
  float p = __builtin_fmaf(u, 0.10294324f, 2.30220820f);  // (2log2e)*0.79788456*(1+0.044715u)
  float e = __builtin_amdgcn_exp2f(x * p);
  float r = __builtin_amdgcn_rcpf(e + 1.0f);
  return __builtin_fmaf(-x, r, x);
}
__device__ __forceinline__ float sigmoidf_(float x) {
  float e = __builtin_amdgcn_exp2f(x * -1.4426950408889634f);
  return __builtin_amdgcn_rcpf(1.0f + e);
}

// ---------------- K1: U/V/Ua/Va precompute --------------------------------
// grid 512, block 256. Block handles 2 embedding rows.
// threads t<128: cons net (k=t); t>=128: assoc net (k=t-128).
__global__ __launch_bounds__(256) void k_uv(
    const float* __restrict__ emb,
    const float* __restrict__ cW1, const float* __restrict__ cb1,
    const float* __restrict__ aW1, const float* __restrict__ ab1,
    float* __restrict__ ws)
{
  __shared__ __align__(16) float sE[2][128];
  const int b = blockIdx.x;
  const int t = threadIdx.x;
  {
    int r = t >> 7, c = t & 127;
    sE[r][c] = emb[(b * 2 + r) * 128 + c];
  }
  __syncthreads();
  const int k = t & 127;
  const bool cons = (t < 128);
  const float* W    = cons ? cW1 : aW1;
  const float* bias = cons ? cb1 : ab1;
  float* outU = ws + (cons ? WS_U : WS_UA);
  float* outV = ws + (cons ? WS_V : WS_VA);
  float accU0 = 0.f, accU1 = 0.f, accV0 = 0.f, accV1 = 0.f;
  for (int c = 0; c < 128; ++c) {
    float wt = W[c * 128 + k];
    float wb = W[(128 + c) * 128 + k];
    float e0 = sE[0][c], e1 = sE[1][c];
    accU0 = __builtin_fmaf(e0, wt, accU0);
    accU1 = __builtin_fmaf(e1, wt, accU1);
    accV0 = __builtin_fmaf(e0, wb, accV0);
    accV1 = __builtin_fmaf(e1, wb, accV1);
  }
  const float bv = bias[k];
  outU[(b * 2 + 0) * 128 + k] = accU0;
  outU[(b * 2 + 1) * 128 + k] = accU1;
  outV[(b * 2 + 0) * 128 + k] = accV0 + bv;
  outV[(b * 2 + 1) * 128 + k] = accV1 + bv;
}

// ---------------- K2: repack W2 matrices into MFMA B-frag order (f32->bf16)
__global__ __launch_bounds__(256) void k_repack(
    const float* __restrict__ cW2,
    const float* __restrict__ aW2,
    unsigned short* __restrict__ frag)
{
  int t = blockIdx.x * 256 + threadIdx.x;  // grid 48 -> 12288
  if (t < 8192) {
    int j = t & 7, lane = (t >> 3) & 63, ks = (t >> 9) & 3, nt = t >> 11;
    frag[t] = (unsigned short)f2bfs(cW2[(ks * 32 + (lane >> 4) * 8 + j) * 64 + nt * 16 + (lane & 15)]);
  } else {
    int u = t - 8192;
    int j = u & 7, lane = (u >> 3) & 63, ks = (u >> 9) & 3, nt = u >> 11;
    frag[t] = (unsigned short)f2bfs(aW2[(ks * 32 + (lane >> 4) * 8 + j) * 32 + nt * 16 + (lane & 15)]);
  }
}

// ---------------- K3: importance head (4 rows per wave, LDS-staged) -------
__global__ __launch_bounds__(256) void k_imp(
    const float* __restrict__ emb, const float* __restrict__ tf,
    const float* __restrict__ iW1, const float* __restrict__ ib1,
    const float* __restrict__ iW2, const float* __restrict__ ib2,
    float* __restrict__ out)
{
  __shared__ __align__(16) float sE[16][136];
  const int t = threadIdx.x;
  const int b = blockIdx.x;   // grid 64
  {
    int r = t >> 4;            // 0..15
    int c = (t & 15) * 8;      // 0..120
    *(float4*)&sE[r][c]     = *(const float4*)(emb + (b * 16 + r) * 128 + c);
    *(float4*)&sE[r][c + 4] = *(const float4*)(emb + (b * 16 + r) * 128 + c + 4);
  }
  if (t < 80) { int r = t / 5, c = t % 5; sE[r][128 + c] = tf[(b * 16 + r) * 5 + c]; }
  __syncthreads();
  const int wave = t >> 6, lane = t & 63;
  float acc[4] = {0.f, 0.f, 0.f, 0.f};
  for (int c = 0; c < 133; ++c) {
    float w1 = iW1[c * 64 + lane];
    #pragma unroll
    for (int q = 0; q < 4; ++q) acc[q] = __builtin_fmaf(sE[wave * 4 + q][c], w1, acc[q]);
  }
  const float w2 = iW2[lane], b1 = ib1[lane], b2 = ib2[0];
  #pragma unroll
  for (int q = 0; q < 4; ++q) {
    float d = geluf(acc[q] + b1) * w2;
    #pragma unroll
    for (int msk = 32; msk; msk >>= 1) d += __shfl_xor(d, msk, 64);
    if (lane == 0) out[2 * P_PAIRS + b * 16 + wave * 4 + q] = sigmoidf_(d + b2);
  }
}

// ---------------- K4: pair kernel -----------------------------------------
// grid (16 jt, 128 ib). Block: 4 waves; wave w owns j = jt*64+w*16+(0..15),
// and loops over TI=8 i values with V/Va held in registers.
// lane: m = lane&15 -> pair row, g = lane>>4 -> k-group; phase-1 results land
// directly in MFMA A-frag layout A[m][k=ks*32+g*8+s].
__global__ __launch_bounds__(256) void k_pairs(
    const float* __restrict__ ws, const unsigned short* __restrict__ frag,
    const float* __restrict__ lng, const float* __restrict__ lnb,
    const float* __restrict__ cb2, const float* __restrict__ cW3,
    const float* __restrict__ cb3,
    const float* __restrict__ ab2, const float* __restrict__ aW3,
    const float* __restrict__ ab3,
    float* __restrict__ out)
{
  const int jt = blockIdx.x;
  const int i0 = blockIdx.y * TI;
  if (jt * 64 + 63 <= i0) return;   // entire tile at/below diagonal

  __shared__ __align__(16) float sU[TI][128];
  __shared__ __align__(16) float sUa[TI][128];
  __shared__ __align__(16) float sG[128];
  __shared__ __align__(16) float sB[128];
  __shared__ __align__(16) unsigned short sFrag[12288];
  const int t = threadIdx.x;
  {
    const uint4* src = (const uint4*)frag;
    uint4* dst = (uint4*)sFrag;
    #pragma unroll
    for (int q = 0; q < 6; ++q) dst[t + q * 256] = src[t + q * 256];
  }
  {
    int r = t >> 5, c4 = (t & 31) * 4;
    *(float4*)&sU[r][c4]  = *(const float4*)(ws + WS_U  + (i0 + r) * 128 + c4);
    *(float4*)&sUa[r][c4] = *(const float4*)(ws + WS_UA + (i0 + r) * 128 + c4);
  }
  if (t < 128) { sG[t] = lng[t]; sB[t] = lnb[t]; }
  __syncthreads();

  const int lane = t & 63;
  const int wave = t >> 6;
  const int m = lane & 15;
  const int g = lane >> 4;
  const int j = jt * 64 + wave * 16 + m;
  const float* Vrow  = ws + WS_V  + j * 128;
  const float* Varow = ws + WS_VA + j * 128;

  // V rows into registers (amortized over TI i-values)
  float vC[4][8], vA[4][8];
  #pragma unroll
  for (int ks = 0; ks < 4; ++ks) {
    const int off = ks * 32 + g * 8;
    float4 a0 = *(const float4*)(Vrow + off);
    float4 a1 = *(const float4*)(Vrow + off + 4);
    vC[ks][0]=a0.x; vC[ks][1]=a0.y; vC[ks][2]=a0.z; vC[ks][3]=a0.w;
    vC[ks][4]=a1.x; vC[ks][5]=a1.y; vC[ks][6]=a1.z; vC[ks][7]=a1.w;
    float4 c0 = *(const float4*)(Varow + off);
    float4 c1 = *(const float4*)(Varow + off + 4);
    vA[ks][0]=c0.x; vA[ks][1]=c0.y; vA[ks][2]=c0.z; vA[ks][3]=c0.w;
    vA[ks][4]=c1.x; vA[ks][5]=c1.y; vA[ks][6]=c1.z; vA[ks][7]=c1.w;
  }

  // hoisted layer-3 constants (per-lane)
  float cb2v[4], cw3v[4], ab2v[2], aw3v[2];
  #pragma unroll
  for (int nt = 0; nt < 4; ++nt) { cb2v[nt] = cb2[nt * 16 + m]; cw3v[nt] = cW3[nt * 16 + m]; }
  #pragma unroll
  for (int nt = 0; nt < 2; ++nt) { ab2v[nt] = ab2[nt * 16 + m]; aw3v[nt] = aW3[nt * 16 + m]; }
  const float cb3s = cb3[0], ab3s = ab3[0];
  const bf16x8* bfr = (const bf16x8*)sFrag;
  const f32x4 zero = {0.f, 0.f, 0.f, 0.f};

  for (int it = 0; it < TI; ++it) {
    const int i = i0 + it;
    if (jt * 64 + wave * 16 + 15 <= i) continue;   // wave-uniform skip
    const float* su  = sU[it];
    const float* sua = sUa[it];

    // ---- cons phase 1: x = U(i)+V(j), LN stats ----
    float xc[4][8];
    float s1 = 0.f, s2 = 0.f;
    #pragma unroll
    for (int ks = 0; ks < 4; ++ks) {
      const int off = ks * 32 + g * 8;
      float4 u0 = *(const float4*)(su + off);
      float4 u1 = *(const float4*)(su + off + 4);
      float us[8] = {u0.x,u0.y,u0.z,u0.w,u1.x,u1.y,u1.z,u1.w};
      #pragma unroll
      for (int s = 0; s < 8; ++s) {
        float x = us[s] + vC[ks][s];
        xc[ks][s] = x; s1 += x; s2 = __builtin_fmaf(x, x, s2);
      }
    }
    s1 += __shfl_xor(s1, 16, 64); s2 += __shfl_xor(s2, 16, 64);
    s1 += __shfl_xor(s1, 32, 64); s2 += __shfl_xor(s2, 32, 64);

    // ---- assoc phase 1 (independent of LN stats -> overlaps shfl latency)
    int4 pA[4];
    #pragma unroll
    for (int ks = 0; ks < 4; ++ks) {
      const int off = ks * 32 + g * 8;
      float4 u0 = *(const float4*)(sua + off);
      float4 u1 = *(const float4*)(sua + off + 4);
      float us[8] = {u0.x,u0.y,u0.z,u0.w,u1.x,u1.y,u1.z,u1.w};
      float r[8];
      #pragma unroll
      for (int s = 0; s < 8; ++s) r[s] = fmaxf(us[s] + vA[ks][s], 0.f);
      pA[ks].x = pk_bf16(r[0], r[1]); pA[ks].y = pk_bf16(r[2], r[3]);
      pA[ks].z = pk_bf16(r[4], r[5]); pA[ks].w = pk_bf16(r[6], r[7]);
    }

    const float mean = s1 * 0.0078125f;
    const float var  = s2 * 0.0078125f - mean * mean;
    const float rstd = rsqrtf(var + 1e-5f);

    int4 pC[4];
    #pragma unroll
    for (int ks = 0; ks < 4; ++ks) {
      const int off = ks * 32 + g * 8;
      float4 g0 = *(const float4*)(sG + off);
      float4 g1 = *(const float4*)(sG + off + 4);
      float4 b0 = *(const float4*)(sB + off);
      float4 b1 = *(const float4*)(sB + off + 4);
      float gg[8] = {g0.x,g0.y,g0.z,g0.w,g1.x,g1.y,g1.z,g1.w};
      float bb[8] = {b0.x,b0.y,b0.z,b0.w,b1.x,b1.y,b1.z,b1.w};
      float y[8];
      #pragma unroll
      for (int s = 0; s < 8; ++s) {
        float tq = (xc[ks][s] - mean) * rstd;
        y[s] = geluf(__builtin_fmaf(tq, gg[s], bb[s]));
      }
      pC[ks].x = pk_bf16(y[0], y[1]); pC[ks].y = pk_bf16(y[2], y[3]);
      pC[ks].z = pk_bf16(y[4], y[5]); pC[ks].w = pk_bf16(y[6], y[7]);
    }

    // ---- layer-2 GEMMs via MFMA ----
    f32x4 accC[4] = {zero, zero, zero, zero};
    f32x4 accA[2] = {zero, zero};
    #pragma unroll
    for (int ks = 0; ks < 4; ++ks) {
      bf16x8 aC = __builtin_bit_cast(bf16x8, pC[ks]);
      bf16x8 aA = __builtin_bit_cast(bf16x8, pA[ks]);
      #pragma unroll
      for (int nt = 0; nt < 4; ++nt)
        accC[nt] = __builtin_amdgcn_mfma_f32_16x16x32_bf16(
            aC, bfr[(nt * 4 + ks) * 64 + lane], accC[nt], 0, 0, 0);
      #pragma unroll
      for (int nt = 0; nt < 2; ++nt)
        accA[nt] = __builtin_amdgcn_mfma_f32_16x16x32_bf16(
            aA, bfr[1024 + (nt * 4 + ks) * 64 + lane], accA[nt], 0, 0, 0);
    }

    // ---- layer 3: bias + act + dot with W3, reduce over n (lane&15) ----
    float sc[4] = {0.f, 0.f, 0.f, 0.f};
    float sa[4] = {0.f, 0.f, 0.f, 0.f};
    #pragma unroll
    for (int nt = 0; nt < 4; ++nt)
      #pragma unroll
      for (int r = 0; r < 4; ++r)
        sc[r] = __builtin_fmaf(geluf(accC[nt][r] + cb2v[nt]), cw3v[nt], sc[r]);
    #pragma unroll
    for (int nt = 0; nt < 2; ++nt)
      #pragma unroll
      for (int r = 0; r < 4; ++r)
        sa[r] = __builtin_fmaf(fmaxf(accA[nt][r] + ab2v[nt], 0.f), aw3v[nt], sa[r]);
    #pragma unroll
    for (int msk = 1; msk <= 8; msk <<= 1) {
      #pragma unroll
      for (int r = 0; r < 4; ++r) {
        sc[r] += __shfl_xor(sc[r], msk, 64);
        sa[r] += __shfl_xor(sa[r], msk, 64);
      }
    }
    if (m < 4) {
      const int jr = jt * 64 + wave * 16 + g * 4 + m;   // pair row g*4 + reg(m)
      if (jr > i) {
        const int p = i * (2 * N_TR - i - 1) / 2 + (jr - i - 1);
        out[p]           = sigmoidf_(sc[m] + cb3s);
        out[P_PAIRS + p] = sigmoidf_(sa[m] + ab3s);
      }
    }
  }
}

extern "C" void kernel_launch(void* const* d_in, const int* in_sizes, int n_in,
                              void* d_out, int out_size, void* d_ws, size_t ws_size,
                              hipStream_t stream) {
  const float* emb = (const float*)d_in[0];
  const float* tf  = (const float*)d_in[1];
  const float* cW1 = (const float*)d_in[2];
  const float* cb1 = (const float*)d_in[3];
  const float* lng = (const float*)d_in[4];
  const float* lnb = (const float*)d_in[5];
  const float* cW2 = (const float*)d_in[6];
  const float* cb2 = (const float*)d_in[7];
  const float* cW3 = (const float*)d_in[8];
  const float* cb3 = (const float*)d_in[9];
  const float* aW1 = (const float*)d_in[10];
  const float* ab1 = (const float*)d_in[11];
  const float* aW2 = (const float*)d_in[12];
  const float* ab2 = (const float*)d_in[13];
  const float* aW3 = (const float*)d_in[14];
  const float* ab3 = (const float*)d_in[15];
  const float* iW1 = (const float*)d_in[16];
  const float* ib1 = (const float*)d_in[17];
  const float* iW2 = (const float*)d_in[18];
  const float* ib2 = (const float*)d_in[19];

  float* ws = (float*)d_ws;
  unsigned short* frag = (unsigned short*)((char*)d_ws + WS_FRAG_BYTES);
  float* out = (float*)d_out;

  hipLaunchKernelGGL(k_uv, dim3(512), dim3(256), 0, stream, emb, cW1, cb1, aW1, ab1, ws);
  hipLaunchKernelGGL(k_repack, dim3(48), dim3(256), 0, stream, cW2, aW2, frag);
  hipLaunchKernelGGL(k_imp, dim3(64), dim3(256), 0, stream, emb, tf, iW1, ib1, iW2, ib2, out);
  hipLaunchKernelGGL(k_pairs, dim3(16, 128), dim3(256), 0, stream,
                     ws, frag, lng, lnb, cb2, cW3, cb3, ab2, aW3, ab3, out);
}